// Round 1
// baseline (302.139 us; speedup 1.0000x reference)
//
#include <hip/hip_runtime.h>
#include <math.h>

// CSR segmented softmax, wave-cooperative LDS staging.
//   - one wave (64 lanes) owns 64 consecutive nodes
//   - the wave's combined edge range is contiguous -> coalesced global ld/st
//   - ragged per-node work happens on LDS only
#define NODES_PER_WAVE 64
#define WAVES_PER_BLOCK 4
#define BLOCK_THREADS (64 * WAVES_PER_BLOCK)      // 256
#define NODES_PER_BLOCK (NODES_PER_WAVE * WAVES_PER_BLOCK)  // 256
#define CAP 2560   // floats per wave LDS slice (2.5x mean range of 1024)

__global__ __launch_bounds__(BLOCK_THREADS, 4)
void seg_softmax_kernel(const int* __restrict__ row_ptr,
                        const float* __restrict__ scores,
                        float* __restrict__ out,
                        int n_nodes) {
    __shared__ float lds[WAVES_PER_BLOCK * CAP];   // 40 KB -> 4 blocks/CU
    const int tid  = threadIdx.x;
    const int wave = tid >> 6;
    const int lane = tid & 63;
    float* buf = &lds[wave * CAP];

    const int base = blockIdx.x * NODES_PER_BLOCK + wave * NODES_PER_WAVE;

    // Clamped row_ptr loads: invalid nodes get empty ranges automatically.
    int i0 = base + lane;     if (i0 > n_nodes) i0 = n_nodes;
    int i1 = base + lane + 1; if (i1 > n_nodes) i1 = n_nodes;
    const int ls = row_ptr[i0];
    const int le = row_ptr[i1];
    const int wstart = __shfl(ls, 0);    // rp[base]
    const int wend   = __shfl(le, 63);   // rp[min(base+64, n)]
    const int range  = wend - wstart;

    if (range <= CAP) {
        // ---- Phase 1: coalesced global -> LDS stage
        for (int j = lane; j < range; j += 64)
            buf[j] = scores[wstart + j];
        __syncthreads();

        // ---- Phase 2: per-lane ragged softmax on LDS (lanes touch disjoint slices)
        const int a = ls - wstart, b = le - wstart;
        float m = -INFINITY;
        for (int j = a; j < b; ++j) m = fmaxf(m, buf[j]);
        float s = 0.0f;
        for (int j = a; j < b; ++j) {
            float e = __expf(buf[j] - m);
            s += e;
            buf[j] = e;          // in-place; only this lane reads [a,b)
        }
        const float rinv = 1.0f / s;   // s >= 1 whenever the loop ran
        for (int j = a; j < b; ++j) buf[j] *= rinv;
        __syncthreads();

        // ---- Phase 3: coalesced LDS -> global store
        for (int j = lane; j < range; j += 64)
            out[wstart + j] = buf[j];
    } else {
        // Slow fallback (range overflows LDS slice) — correctness only, ~never
        // taken on this data. Barrier count matches the fast path.
        __syncthreads();
        float m = -INFINITY;
        for (int j = ls; j < le; ++j) m = fmaxf(m, scores[j]);
        float s = 0.0f;
        for (int j = ls; j < le; ++j) {
            float e = __expf(scores[j] - m);
            s += e;
            out[j] = e;
        }
        const float rinv = 1.0f / s;
        for (int j = ls; j < le; ++j) out[j] *= rinv;
        __syncthreads();
    }
}

extern "C" void kernel_launch(void* const* d_in, const int* in_sizes, int n_in,
                              void* d_out, int out_size, void* d_ws, size_t ws_size,
                              hipStream_t stream) {
    const int*   row_ptr = (const int*)d_in[0];
    const float* scores  = (const float*)d_in[1];
    float*       out     = (float*)d_out;
    const int n_nodes = in_sizes[0] - 1;
    const int blocks  = (n_nodes + NODES_PER_BLOCK - 1) / NODES_PER_BLOCK;
    seg_softmax_kernel<<<blocks, BLOCK_THREADS, 0, stream>>>(row_ptr, scores, out, n_nodes);
}